// Round 4
// baseline (703.910 us; speedup 1.0000x reference)
//
#include <hip/hip_runtime.h>

typedef unsigned short u16;
typedef unsigned long long u64;
typedef __attribute__((ext_vector_type(8))) short short8;
typedef __attribute__((ext_vector_type(4))) float f32x4;

#define B_ 2048
#define D_ 512
#define CB_ 2048
#define K_ 200

__device__ __forceinline__ u16 f2bf_rne(float f) {
    unsigned u = __float_as_uint(f);
    unsigned r = (u + 0x7fffu + ((u >> 16) & 1u)) >> 16;
    return (u16)r;
}

// ---------------- init: diffacc = 0 ----------------
__global__ void init_kernel(float* diffacc) {
    if (threadIdx.x == 0) diffacc[0] = 0.0f;
}

// ---------------- codebook fp32 -> bf16 ----------------
__global__ void cvt_cb_kernel(const float* __restrict__ cb, u16* __restrict__ ch) {
    int i = blockIdx.x * 256 + threadIdx.x;      // 262144 float4s
    float4 v = ((const float4*)cb)[i];
    ushort4 o;
    o.x = f2bf_rne(v.x); o.y = f2bf_rne(v.y); o.z = f2bf_rne(v.z); o.w = f2bf_rne(v.w);
    ((ushort4*)ch)[i] = o;
}

// ---------------- codebook row norms: fp64 exact -> fp32 ----------------
__global__ void cnorm_kernel(const float* __restrict__ cb, float* __restrict__ cnormf) {
    __shared__ double red[256];
    int j = blockIdx.x, t = threadIdx.x;
    float2 v = ((const float2*)(cb + (size_t)j * D_))[t];
    double a = (double)v.x, b = (double)v.y;
    red[t] = a * a + b * b;
    __syncthreads();
    for (int s = 128; s > 0; s >>= 1) {
        if (t < s) red[t] += red[t + s];
        __syncthreads();
    }
    if (t == 0) cnormf[j] = (float)red[0];
}

// ---------------- masked mean over history -> out0 slot (fp32) ----------------
__global__ void mean_kernel(const int* __restrict__ items,
                            const float* __restrict__ item_embed,
                            float* __restrict__ mean) {
    __shared__ int sidx[K_];
    int b = blockIdx.x, t = threadIdx.x;   // 128 threads
    for (int k = t; k < K_; k += 128) sidx[k] = items[b * K_ + k];
    __syncthreads();
    int c = t * 4;
    float s0 = 0.f, s1 = 0.f, s2 = 0.f, s3 = 0.f;
    int cnt = 0;
    for (int k = 0; k < K_; k++) {
        int idx = sidx[k];
        if (idx != 0) {
            cnt++;
            float4 v = *(const float4*)(item_embed + (size_t)idx * D_ + c);
            s0 += v.x; s1 += v.y; s2 += v.z; s3 += v.w;
        }
    }
    float inv = 1.0f / (float)cnt;
    float4 o; o.x = s0 * inv; o.y = s1 * inv; o.z = s2 * inv; o.w = s3 * inv;
    *(float4*)(mean + (size_t)b * D_ + c) = o;
}

// ---------------- GEMM1: h = relu(mean @ W1 + b1), W1 [512][1024] ----------------
// grid 256 blocks, 256 threads; 8 users/block, 4 j/thread
__global__ void gemm1_kernel(const float* __restrict__ mean,
                             const float* __restrict__ W1,
                             const float* __restrict__ b1,
                             float* __restrict__ h) {
    __shared__ float sm[8 * 512];
    int t = threadIdx.x;
    int u0 = blockIdx.x * 8;
    for (int i = t; i < 1024; i += 256)
        ((float4*)sm)[i] = ((const float4*)(mean + (size_t)u0 * 512))[i];
    __syncthreads();
    int j = t * 4;
    float acc[8][4];
#pragma unroll
    for (int q = 0; q < 8; q++)
#pragma unroll
        for (int r = 0; r < 4; r++) acc[q][r] = 0.f;
    for (int d = 0; d < 512; d += 4) {
        float4 w0 = *(const float4*)(W1 + (size_t)(d + 0) * 1024 + j);
        float4 w1 = *(const float4*)(W1 + (size_t)(d + 1) * 1024 + j);
        float4 w2 = *(const float4*)(W1 + (size_t)(d + 2) * 1024 + j);
        float4 w3 = *(const float4*)(W1 + (size_t)(d + 3) * 1024 + j);
#pragma unroll
        for (int q = 0; q < 8; q++) {
            float4 a = *(const float4*)(sm + q * 512 + d);
            acc[q][0] += a.x * w0.x + a.y * w1.x + a.z * w2.x + a.w * w3.x;
            acc[q][1] += a.x * w0.y + a.y * w1.y + a.z * w2.y + a.w * w3.y;
            acc[q][2] += a.x * w0.z + a.y * w1.z + a.z * w2.z + a.w * w3.z;
            acc[q][3] += a.x * w0.w + a.y * w1.w + a.z * w2.w + a.w * w3.w;
        }
    }
    float4 bb = *(const float4*)(b1 + j);
#pragma unroll
    for (int q = 0; q < 8; q++) {
        float4 o;
        o.x = acc[q][0] + bb.x; o.y = acc[q][1] + bb.y;
        o.z = acc[q][2] + bb.z; o.w = acc[q][3] + bb.w;
        o.x = o.x > 0.f ? o.x : 0.f; o.y = o.y > 0.f ? o.y : 0.f;
        o.z = o.z > 0.f ? o.z : 0.f; o.w = o.w > 0.f ? o.w : 0.f;
        *(float4*)(h + (size_t)(u0 + q) * 1024 + j) = o;
    }
}

// ---------------- GEMM2: u = h @ W2 + b2 -> out4 (fp32, scalar: unaligned) + uh (bf16) ----------------
// grid 256 blocks, 128 threads; 8 users/block, 4 j/thread
__global__ void gemm2_kernel(const float* __restrict__ h,
                             const float* __restrict__ W2,
                             const float* __restrict__ b2,
                             float* __restrict__ out_ue,
                             u16* __restrict__ uh) {
    __shared__ float sh[8 * 1024];
    int t = threadIdx.x;
    int u0 = blockIdx.x * 8;
    for (int i = t; i < 2048; i += 128)
        ((float4*)sh)[i] = ((const float4*)(h + (size_t)u0 * 1024))[i];
    __syncthreads();
    int j = t * 4;
    float acc[8][4];
#pragma unroll
    for (int q = 0; q < 8; q++)
#pragma unroll
        for (int r = 0; r < 4; r++) acc[q][r] = 0.f;
    for (int d = 0; d < 1024; d += 4) {
        float4 w0 = *(const float4*)(W2 + (size_t)(d + 0) * 512 + j);
        float4 w1 = *(const float4*)(W2 + (size_t)(d + 1) * 512 + j);
        float4 w2 = *(const float4*)(W2 + (size_t)(d + 2) * 512 + j);
        float4 w3 = *(const float4*)(W2 + (size_t)(d + 3) * 512 + j);
#pragma unroll
        for (int q = 0; q < 8; q++) {
            float4 a = *(const float4*)(sh + q * 1024 + d);
            acc[q][0] += a.x * w0.x + a.y * w1.x + a.z * w2.x + a.w * w3.x;
            acc[q][1] += a.x * w0.y + a.y * w1.y + a.z * w2.y + a.w * w3.y;
            acc[q][2] += a.x * w0.z + a.y * w1.z + a.z * w2.z + a.w * w3.z;
            acc[q][3] += a.x * w0.w + a.y * w1.w + a.z * w2.w + a.w * w3.w;
        }
    }
    float4 bb = *(const float4*)(b2 + j);
#pragma unroll
    for (int q = 0; q < 8; q++) {
        float v0 = acc[q][0] + bb.x, v1 = acc[q][1] + bb.y;
        float v2 = acc[q][2] + bb.z, v3 = acc[q][3] + bb.w;
        size_t o = (size_t)(u0 + q) * 512 + j;
        out_ue[o]     = v0;   // out4 base is odd-float offset: scalar stores
        out_ue[o + 1] = v1;
        out_ue[o + 2] = v2;
        out_ue[o + 3] = v3;
        ushort4 hb;
        hb.x = f2bf_rne(v0); hb.y = f2bf_rne(v1);
        hb.z = f2bf_rne(v2); hb.w = f2bf_rne(v3);
        *(ushort4*)(uh + o) = hb;
    }
}

// ---------------- VQ score via bf16 MFMA: d2 = cnorm - 2 * (U . C^T) ----------------
// grid 1024 blocks x 256 threads = 4096 waves.
// wave gw: ustrip = gw>>5 (16 users), jstrip = gw&31 (64 codewords = 4 MFMA j-tiles)
__device__ __forceinline__ u64 shfl_xor_u64(u64 v, int m) {
    int lo = __shfl_xor((int)(v & 0xffffffffu), m);
    int hi = __shfl_xor((int)(v >> 32), m);
    return ((u64)(unsigned)hi << 32) | (unsigned)lo;
}

__global__ void score_mfma(const u16* __restrict__ uh,
                           const u16* __restrict__ ch,
                           const float* __restrict__ cnormf,
                           u64* __restrict__ pminS) {
    int t = threadIdx.x;
    int lane = t & 63;
    int gw = blockIdx.x * 4 + (t >> 6);
    int u0 = (gw >> 5) * 16;
    int j0 = (gw & 31) * 64;
    int mrow = lane & 15, quad = lane >> 4;

    short8 af[16];
    const u16* ubase = uh + (size_t)(u0 + mrow) * 512 + quad * 8;
#pragma unroll
    for (int ks = 0; ks < 16; ks++) af[ks] = *(const short8*)(ubase + ks * 32);

    u64 best[4] = {~0ull, ~0ull, ~0ull, ~0ull};
    for (int jt = 0; jt < 4; jt++) {
        int jb = j0 + jt * 16;
        const u16* cbase = ch + (size_t)(jb + mrow) * 512 + quad * 8;
        f32x4 acc = {0.f, 0.f, 0.f, 0.f};
#pragma unroll
        for (int ks = 0; ks < 16; ks++) {
            short8 bf = *(const short8*)(cbase + ks * 32);
            acc = __builtin_amdgcn_mfma_f32_16x16x32_bf16(af[ks], bf, acc, 0, 0, 0);
        }
        int n = jb + mrow;                    // D col = lane&15
        float cn = cnormf[n];
#pragma unroll
        for (int r = 0; r < 4; r++) {         // D row (user) = quad*4 + r
            float d2 = cn - 2.0f * acc[r];    // ~512 > 0 always
            u64 p = (((u64)__float_as_uint(d2)) << 32) | (unsigned)n;
            if (p < best[r]) best[r] = p;
        }
    }
    // min across the 16 lanes of each quad-row group (xor 1,2,4,8 stays in-group)
#pragma unroll
    for (int off = 8; off >= 1; off >>= 1) {
#pragma unroll
        for (int r = 0; r < 4; r++) {
            u64 o = shfl_xor_u64(best[r], off);
            if (o < best[r]) best[r] = o;
        }
    }
    if (mrow == 0) {
#pragma unroll
        for (int r = 0; r < 4; r++) {
            int user = u0 + quad * 4 + r;
            pminS[(size_t)user * 32 + (gw & 31)] = best[r];
        }
    }
}

// ---------------- straight-through output + commitment loss partials ----------------
__global__ void finalize_user(const u64* __restrict__ pminS,
                              const float* __restrict__ ub,
                              const float* __restrict__ cb,
                              float* __restrict__ out0,
                              float* __restrict__ diffacc) {
    __shared__ u64 sm64[32];
    __shared__ unsigned sbest;
    __shared__ float red[256];
    int b = blockIdx.x, t = threadIdx.x;
    if (t < 32) sm64[t] = pminS[(size_t)b * 32 + t];
    __syncthreads();
    if (t == 0) {
        u64 m = sm64[0];
#pragma unroll
        for (int i = 1; i < 32; i++) if (sm64[i] < m) m = sm64[i];
        sbest = (unsigned)(m & 0xffffffffu);
    }
    __syncthreads();
    unsigned bestj = sbest;
    int c = t * 2;
    float2 qv = ((const float2*)(cb + (size_t)bestj * 512))[t];
    float w0 = ub[(size_t)b * 512 + c];
    float w1 = ub[(size_t)b * 512 + c + 1];
    float2 o;
    o.x = w0 + (qv.x - w0);
    o.y = w1 + (qv.y - w1);
    ((float2*)(out0 + (size_t)b * 512))[t] = o;
    float d0 = qv.x - w0, d1 = qv.y - w1;
    red[t] = d0 * d0 + d1 * d1;
    __syncthreads();
    for (int s = 128; s > 0; s >>= 1) {
        if (t < s) red[t] += red[t + s];
        __syncthreads();
    }
    if (t == 0) atomicAdd(diffacc, red[0]);
}

// ---------------- pos/neg gathers (fp32 float4 copy) ----------------
__global__ void gather_pn(const int* __restrict__ pos, const int* __restrict__ neg,
                          const float* __restrict__ ie,
                          float* __restrict__ out1, float* __restrict__ out2) {
    int b = blockIdx.x, t = threadIdx.x;  // 128 threads
    int p = pos[b], n = neg[b];
    ((float4*)(out1 + (size_t)b * 512))[t] = ((const float4*)(ie + (size_t)p * 512))[t];
    ((float4*)(out2 + (size_t)b * 512))[t] = ((const float4*)(ie + (size_t)n * 512))[t];
}

// ---------------- diff scalar ----------------
__global__ void diff_final(const float* __restrict__ diffacc, float* __restrict__ out3) {
    if (threadIdx.x == 0)
        out3[0] = diffacc[0] * (1.0f / ((float)B_ * (float)D_));
}

extern "C" void kernel_launch(void* const* d_in, const int* in_sizes, int n_in,
                              void* d_out, int out_size, void* d_ws, size_t ws_size,
                              hipStream_t stream) {
    const int* items = (const int*)d_in[1];
    const int* pos   = (const int*)d_in[2];
    const int* neg   = (const int*)d_in[3];
    const float* item_embed = (const float*)d_in[4];
    const float* W1 = (const float*)d_in[5];
    const float* b1 = (const float*)d_in[6];
    const float* W2 = (const float*)d_in[7];
    const float* b2 = (const float*)d_in[8];
    const float* cb = (const float*)d_in[9];

    float* out0 = (float*)d_out;             // quant_user [B,D] — doubles as mean buffer
    float* out1 = out0 + (size_t)B_ * D_;    // pos_item  — doubles as hbuf low half
    float* out2 = out1 + (size_t)B_ * D_;    // neg_item  — doubles as hbuf high half
    float* out3 = out2 + (size_t)B_ * D_;    // diff scalar
    float* out4 = out3 + 1;                  // user_embed [B,D] — doubles as u buffer (odd offset)

    float* hbuf = out1;                      // B*1024 fp32 = 8 MB, overwritten by gather_pn later

    // workspace layout (~4.7 MB):
    char* wsb = (char*)d_ws;
    u16* uh      = (u16*)wsb;                        // B*D bf16      = 2 MB
    u16* ch      = (u16*)(wsb + 2097152);            // CB*D bf16     = 2 MB
    u64* pminS   = (u64*)(wsb + 4194304);            // B*32 u64      = 512 KB
    float* cnormf = (float*)(wsb + 4718592);         // CB fp32       = 8 KB
    float* diffacc = (float*)(wsb + 4726784);        // 1 float

    init_kernel<<<dim3(1), dim3(64), 0, stream>>>(diffacc);
    cvt_cb_kernel<<<dim3(1024), dim3(256), 0, stream>>>(cb, ch);
    cnorm_kernel<<<dim3(CB_), dim3(256), 0, stream>>>(cb, cnormf);
    mean_kernel<<<dim3(B_), dim3(128), 0, stream>>>(items, item_embed, out0);
    gemm1_kernel<<<dim3(256), dim3(256), 0, stream>>>(out0, W1, b1, hbuf);
    gemm2_kernel<<<dim3(256), dim3(128), 0, stream>>>(hbuf, W2, b2, out4, uh);
    score_mfma<<<dim3(1024), dim3(256), 0, stream>>>(uh, ch, cnormf, pminS);
    finalize_user<<<dim3(B_), dim3(256), 0, stream>>>(pminS, out4, cb, out0, diffacc);
    gather_pn<<<dim3(B_), dim3(128), 0, stream>>>(pos, neg, item_embed, out1, out2);
    diff_final<<<dim3(1), dim3(64), 0, stream>>>(diffacc, out3);
}

// Round 5
// 504.134 us; speedup vs baseline: 1.3963x; 1.3963x over previous
//
#include <hip/hip_runtime.h>

typedef unsigned short u16;
typedef unsigned long long u64;
typedef __attribute__((ext_vector_type(8))) short short8;
typedef __attribute__((ext_vector_type(4))) float f32x4;

#define B_ 2048
#define D_ 512
#define CB_ 2048
#define K_ 200

__device__ __forceinline__ u16 f2bf_rne(float f) {
    unsigned u = __float_as_uint(f);
    unsigned r = (u + 0x7fffu + ((u >> 16) & 1u)) >> 16;
    return (u16)r;
}

__device__ __forceinline__ u64 shfl_xor_u64(u64 v, int m) {
    int lo = __shfl_xor((int)(v & 0xffffffffu), m);
    int hi = __shfl_xor((int)(v >> 32), m);
    return ((u64)(unsigned)hi << 32) | (unsigned)lo;
}

// ---------------- prep: cb fp32 -> bf16 rows + fp64-exact row norms + diffacc=0 ----------------
// grid CB_ blocks x 128 thr; block j handles one codebook row
__global__ void cbprep_kernel(const float* __restrict__ cb, u16* __restrict__ ch,
                              float* __restrict__ cnormf, float* __restrict__ diffacc) {
    __shared__ double red[128];
    int j = blockIdx.x, t = threadIdx.x;
    float4 v = ((const float4*)(cb + (size_t)j * D_))[t];
    ushort4 o;
    o.x = f2bf_rne(v.x); o.y = f2bf_rne(v.y); o.z = f2bf_rne(v.z); o.w = f2bf_rne(v.w);
    ((ushort4*)(ch + (size_t)j * D_))[t] = o;
    red[t] = (double)v.x * v.x + (double)v.y * v.y + (double)v.z * v.z + (double)v.w * v.w;
    __syncthreads();
    for (int s = 64; s > 0; s >>= 1) {
        if (t < s) red[t] += red[t + s];
        __syncthreads();
    }
    if (t == 0) {
        cnormf[j] = (float)red[0];
        if (j == 0) diffacc[0] = 0.0f;
    }
}

// ---------------- W [K][N] fp32 -> WT [N][K] bf16, 32x32 tiles ----------------
__global__ void transpose_w(const float* __restrict__ W, u16* __restrict__ WT, int K, int N) {
    __shared__ float tile[32][33];
    int n0 = blockIdx.x * 32, k0 = blockIdx.y * 32;
    int t = threadIdx.x;
    int kl = t >> 3, nl = (t & 7) * 4;
    float4 v = *(const float4*)(W + (size_t)(k0 + kl) * N + n0 + nl);
    tile[kl][nl] = v.x; tile[kl][nl + 1] = v.y; tile[kl][nl + 2] = v.z; tile[kl][nl + 3] = v.w;
    __syncthreads();
    int nl2 = t >> 3, kl2 = (t & 7) * 4;
    ushort4 o;
    o.x = f2bf_rne(tile[kl2][nl2]);
    o.y = f2bf_rne(tile[kl2 + 1][nl2]);
    o.z = f2bf_rne(tile[kl2 + 2][nl2]);
    o.w = f2bf_rne(tile[kl2 + 3][nl2]);
    *(ushort4*)(WT + (size_t)(n0 + nl2) * K + k0 + kl2) = o;
}

// ---------------- masked mean over history -> bf16 ----------------
__global__ void mean_kernel(const int* __restrict__ items,
                            const float* __restrict__ item_embed,
                            u16* __restrict__ meanb) {
    __shared__ int sidx[K_];
    int b = blockIdx.x, t = threadIdx.x;   // 128 threads
    for (int k = t; k < K_; k += 128) sidx[k] = items[b * K_ + k];
    __syncthreads();
    int c = t * 4;
    float s0 = 0.f, s1 = 0.f, s2 = 0.f, s3 = 0.f;
    int cnt = 0;
    for (int k = 0; k < K_; k++) {
        int idx = sidx[k];
        if (idx != 0) {
            cnt++;
            float4 v = *(const float4*)(item_embed + (size_t)idx * D_ + c);
            s0 += v.x; s1 += v.y; s2 += v.z; s3 += v.w;
        }
    }
    float inv = 1.0f / (float)cnt;
    ushort4 o;
    o.x = f2bf_rne(s0 * inv); o.y = f2bf_rne(s1 * inv);
    o.z = f2bf_rne(s2 * inv); o.w = f2bf_rne(s3 * inv);
    *(ushort4*)(meanb + (size_t)b * D_ + c) = o;
}

// ---------------- GEMM1 (MFMA): h = relu(mean @ W1 + b1) -> hb bf16 [2048][1024] ----------------
// 1024 blocks x 256 thr = 4096 waves; wave tile 16(M) x 32(N), K=512, no LDS
__global__ void gemm1_mfma(const u16* __restrict__ meanb, const u16* __restrict__ W1T,
                           const float* __restrict__ b1w, u16* __restrict__ hb) {
    int t = threadIdx.x;
    int wid = blockIdx.x * 4 + (t >> 6);
    int lane = t & 63;
    int mt = wid >> 5, nt = wid & 31;
    int m0 = mt * 16, n0 = nt * 32;
    int mr = lane & 15, quad = lane >> 4, kb = quad * 8;
    const u16* ap  = meanb + (size_t)(m0 + mr) * 512 + kb;
    const u16* bp0 = W1T + (size_t)(n0 + mr) * 512 + kb;
    const u16* bp1 = bp0 + 16 * 512;
    f32x4 acc0 = {0.f, 0.f, 0.f, 0.f}, acc1 = {0.f, 0.f, 0.f, 0.f};
#pragma unroll
    for (int ks = 0; ks < 16; ks++) {
        short8 a  = *(const short8*)(ap  + ks * 32);
        short8 b0 = *(const short8*)(bp0 + ks * 32);
        short8 b1 = *(const short8*)(bp1 + ks * 32);
        acc0 = __builtin_amdgcn_mfma_f32_16x16x32_bf16(a, b0, acc0, 0, 0, 0);
        acc1 = __builtin_amdgcn_mfma_f32_16x16x32_bf16(a, b1, acc1, 0, 0, 0);
    }
    float bias0 = b1w[n0 + mr], bias1 = b1w[n0 + 16 + mr];
#pragma unroll
    for (int r = 0; r < 4; r++) {
        int m = m0 + quad * 4 + r;
        float v0 = acc0[r] + bias0; v0 = v0 > 0.f ? v0 : 0.f;
        float v1 = acc1[r] + bias1; v1 = v1 > 0.f ? v1 : 0.f;
        hb[(size_t)m * 1024 + n0 + mr]      = f2bf_rne(v0);
        hb[(size_t)m * 1024 + n0 + 16 + mr] = f2bf_rne(v1);
    }
}

// ---------------- GEMM2 (MFMA): u = h @ W2 + b2 -> out4 fp32 + uh bf16 ----------------
// 1024 blocks x 256 thr = 4096 waves; wave tile 16(M) x 16(N), K=1024 split into 2 chains
__global__ void gemm2_mfma(const u16* __restrict__ hb, const u16* __restrict__ W2T,
                           const float* __restrict__ b2w,
                           float* __restrict__ out_ue, u16* __restrict__ uh) {
    int t = threadIdx.x;
    int wid = blockIdx.x * 4 + (t >> 6);
    int lane = t & 63;
    int mt = wid >> 5, nt = wid & 31;
    int m0 = mt * 16, n0 = nt * 16;
    int mr = lane & 15, quad = lane >> 4, kb = quad * 8;
    const u16* ap = hb  + (size_t)(m0 + mr) * 1024 + kb;
    const u16* bp = W2T + (size_t)(n0 + mr) * 1024 + kb;
    f32x4 acc0 = {0.f, 0.f, 0.f, 0.f}, acc1 = {0.f, 0.f, 0.f, 0.f};
#pragma unroll
    for (int ks = 0; ks < 16; ks++) {
        short8 a0 = *(const short8*)(ap + ks * 32);
        short8 b0 = *(const short8*)(bp + ks * 32);
        short8 a1 = *(const short8*)(ap + 512 + ks * 32);
        short8 b1 = *(const short8*)(bp + 512 + ks * 32);
        acc0 = __builtin_amdgcn_mfma_f32_16x16x32_bf16(a0, b0, acc0, 0, 0, 0);
        acc1 = __builtin_amdgcn_mfma_f32_16x16x32_bf16(a1, b1, acc1, 0, 0, 0);
    }
    float bias = b2w[n0 + mr];
#pragma unroll
    for (int r = 0; r < 4; r++) {
        int m = m0 + quad * 4 + r;
        float v = acc0[r] + acc1[r] + bias;
        size_t o = (size_t)m * 512 + n0 + mr;
        out_ue[o] = v;              // out4 base is odd-float offset: scalar stores
        uh[o] = f2bf_rne(v);
    }
}

// ---------------- VQ score (MFMA): d2 = cnorm - 2*(U.C^T); block = 16 users x 256 j ----------------
// 1024 blocks x 256 thr; pminS[user][jstrip] over 8 jstrips
__global__ void score_mfma(const u16* __restrict__ uh,
                           const u16* __restrict__ ch,
                           const float* __restrict__ cnormf,
                           u64* __restrict__ pminS) {
    __shared__ u64 red2[64];
    int t = threadIdx.x, lane = t & 63, w = t >> 6;
    int ustrip = blockIdx.x >> 3, jstrip = blockIdx.x & 7;
    int u0 = ustrip * 16;
    int j0 = jstrip * 256 + w * 64;
    int mr = lane & 15, quad = lane >> 4, kb = quad * 8;

    short8 af[16];
    const u16* ap = uh + (size_t)(u0 + mr) * 512 + kb;
#pragma unroll
    for (int ks = 0; ks < 16; ks++) af[ks] = *(const short8*)(ap + ks * 32);

    u64 best[4] = {~0ull, ~0ull, ~0ull, ~0ull};
    for (int jt = 0; jt < 4; jt++) {
        int jb = j0 + jt * 16;
        const u16* bp = ch + (size_t)(jb + mr) * 512 + kb;
        f32x4 acc = {0.f, 0.f, 0.f, 0.f};
#pragma unroll
        for (int ks = 0; ks < 16; ks++) {
            short8 bv = *(const short8*)(bp + ks * 32);
            acc = __builtin_amdgcn_mfma_f32_16x16x32_bf16(af[ks], bv, acc, 0, 0, 0);
        }
        int n = jb + mr;
        float cn = cnormf[n];
#pragma unroll
        for (int r = 0; r < 4; r++) {
            float d2 = cn - 2.0f * acc[r];   // ~400-650 > 0 always
            u64 p = (((u64)__float_as_uint(d2)) << 32) | (unsigned)n;
            if (p < best[r]) best[r] = p;
        }
    }
#pragma unroll
    for (int off = 8; off >= 1; off >>= 1)
#pragma unroll
        for (int r = 0; r < 4; r++) {
            u64 o = shfl_xor_u64(best[r], off);
            if (o < best[r]) best[r] = o;
        }
    if (mr == 0) {
#pragma unroll
        for (int r = 0; r < 4; r++) red2[w * 16 + quad * 4 + r] = best[r];
    }
    __syncthreads();
    if (t < 16) {
        u64 m = red2[t];
#pragma unroll
        for (int ww = 1; ww < 4; ww++) {
            u64 v = red2[ww * 16 + t];
            if (v < m) m = v;
        }
        pminS[(size_t)(u0 + t) * 8 + jstrip] = m;
    }
}

// ---------------- straight-through output + commitment loss partials ----------------
__global__ void finalize_user(const u64* __restrict__ pminS,
                              const float* __restrict__ ub,
                              const float* __restrict__ cb,
                              float* __restrict__ out0,
                              float* __restrict__ diffacc) {
    __shared__ u64 sm64[8];
    __shared__ unsigned sbest;
    __shared__ float red[256];
    int b = blockIdx.x, t = threadIdx.x;
    if (t < 8) sm64[t] = pminS[(size_t)b * 8 + t];
    __syncthreads();
    if (t == 0) {
        u64 m = sm64[0];
#pragma unroll
        for (int i = 1; i < 8; i++) if (sm64[i] < m) m = sm64[i];
        sbest = (unsigned)(m & 0xffffffffu);
    }
    __syncthreads();
    unsigned bestj = sbest;
    int c = t * 2;
    float2 qv = ((const float2*)(cb + (size_t)bestj * 512))[t];
    float w0 = ub[(size_t)b * 512 + c];
    float w1 = ub[(size_t)b * 512 + c + 1];
    float2 o;
    o.x = w0 + (qv.x - w0);
    o.y = w1 + (qv.y - w1);
    ((float2*)(out0 + (size_t)b * 512))[t] = o;
    float d0 = qv.x - w0, d1 = qv.y - w1;
    red[t] = d0 * d0 + d1 * d1;
    __syncthreads();
    for (int s = 128; s > 0; s >>= 1) {
        if (t < s) red[t] += red[t + s];
        __syncthreads();
    }
    if (t == 0) atomicAdd(diffacc, red[0]);
}

// ---------------- pos/neg gathers (fp32 float4 copy) ----------------
__global__ void gather_pn(const int* __restrict__ pos, const int* __restrict__ neg,
                          const float* __restrict__ ie,
                          float* __restrict__ out1, float* __restrict__ out2) {
    int b = blockIdx.x, t = threadIdx.x;  // 128 threads
    int p = pos[b], n = neg[b];
    ((float4*)(out1 + (size_t)b * 512))[t] = ((const float4*)(ie + (size_t)p * 512))[t];
    ((float4*)(out2 + (size_t)b * 512))[t] = ((const float4*)(ie + (size_t)n * 512))[t];
}

// ---------------- diff scalar ----------------
__global__ void diff_final(const float* __restrict__ diffacc, float* __restrict__ out3) {
    if (threadIdx.x == 0)
        out3[0] = diffacc[0] * (1.0f / ((float)B_ * (float)D_));
}

extern "C" void kernel_launch(void* const* d_in, const int* in_sizes, int n_in,
                              void* d_out, int out_size, void* d_ws, size_t ws_size,
                              hipStream_t stream) {
    const int* items = (const int*)d_in[1];
    const int* pos   = (const int*)d_in[2];
    const int* neg   = (const int*)d_in[3];
    const float* item_embed = (const float*)d_in[4];
    const float* W1 = (const float*)d_in[5];
    const float* b1 = (const float*)d_in[6];
    const float* W2 = (const float*)d_in[7];
    const float* b2 = (const float*)d_in[8];
    const float* cb = (const float*)d_in[9];

    float* out0 = (float*)d_out;             // quant_user [B,D]
    float* out1 = out0 + (size_t)B_ * D_;    // pos_item — doubles as hb (bf16 [2048][1024] = 4 MB)
    float* out2 = out1 + (size_t)B_ * D_;    // neg_item
    float* out3 = out2 + (size_t)B_ * D_;    // diff scalar
    float* out4 = out3 + 1;                  // user_embed [B,D] — doubles as u buffer (odd offset)

    u16* hb = (u16*)out1;                    // 4 MB bf16, overwritten by gather_pn at the end

    // workspace layout (8.528 MB, ws >= 8.536 MB proven in round 3):
    char* wsb = (char*)d_ws;
    u16* meanb = (u16*)wsb;                          // 2 MB  [0, 2M)
    u16* W1T   = (u16*)(wsb + 2097152);              // 1 MB  [2M, 3M)
    u16* W2T   = (u16*)(wsb + 3145728);              // 1 MB  [3M, 4M)
    u16* uh    = (u16*)(wsb + 4194304);              // 2 MB  [4M, 6M)
    u16* ch    = (u16*)(wsb + 6291456);              // 2 MB  [6M, 8M)
    u64* pminS = (u64*)(wsb + 8388608);              // 128 KB
    float* cnormf  = (float*)(wsb + 8519680);        // 8 KB
    float* diffacc = (float*)(wsb + 8527872);        // 4 B

    cbprep_kernel<<<dim3(CB_), dim3(128), 0, stream>>>(cb, ch, cnormf, diffacc);
    transpose_w<<<dim3(32, 16), dim3(256), 0, stream>>>(W1, W1T, 512, 1024);
    transpose_w<<<dim3(16, 32), dim3(256), 0, stream>>>(W2, W2T, 1024, 512);
    mean_kernel<<<dim3(B_), dim3(128), 0, stream>>>(items, item_embed, meanb);
    gemm1_mfma<<<dim3(1024), dim3(256), 0, stream>>>(meanb, W1T, b1, hb);
    gemm2_mfma<<<dim3(1024), dim3(256), 0, stream>>>(hb, W2T, b2, out4, uh);
    score_mfma<<<dim3(1024), dim3(256), 0, stream>>>(uh, ch, cnormf, pminS);
    finalize_user<<<dim3(B_), dim3(256), 0, stream>>>(pminS, out4, cb, out0, diffacc);
    gather_pn<<<dim3(B_), dim3(128), 0, stream>>>(pos, neg, item_embed, out1, out2);
    diff_final<<<dim3(1), dim3(64), 0, stream>>>(diffacc, out3);
}